// Round 2
// baseline (437.205 us; speedup 1.0000x reference)
//
#include <hip/hip_runtime.h>
#include <hip/hip_bf16.h>

// B=4, S=2048, D=1024, H=16, HD=64. fp32 in/out, bf16 MFMA compute inside.
#define NB 4
#define NS 2048
#define ND 1024
#define NH 16

typedef __attribute__((ext_vector_type(8))) short short8;
typedef __attribute__((ext_vector_type(4))) float f32x4;

__device__ __forceinline__ unsigned short f2b(float f) {
  unsigned int u = __float_as_uint(f);
  u = (u + 0x7fffu + ((u >> 16) & 1u)) >> 16;   // RNE to bf16
  return (unsigned short)u;
}
__device__ __forceinline__ unsigned int pkbf(float a, float b) {
  return (unsigned int)f2b(a) | ((unsigned int)f2b(b) << 16);
}
__device__ __forceinline__ void gload16(const void* g, void* l) {
  __builtin_amdgcn_global_load_lds(
      (const __attribute__((address_space(1))) unsigned int*)g,
      (__attribute__((address_space(3))) unsigned int*)l, 16, 0, 0);
}
__device__ __forceinline__ int sw2(int row) { return (row ^ (row >> 2)) & 3; }

// ---------------- cast x -> bf16 ----------------
__global__ void conv_x(const float* __restrict__ x, unsigned short* __restrict__ xb) {
  int i = blockIdx.x * 256 + threadIdx.x;
  float4 v = ((const float4*)x)[i];
  ushort4 o;
  o.x = f2b(v.x); o.y = f2b(v.y); o.z = f2b(v.z); o.w = f2b(v.w);
  ((ushort4*)xb)[i] = o;
}

// ---------------- transpose + cast W[k][n] -> Wt_bf16[n][k] ----------------
__global__ void conv_wt(const float* __restrict__ Wq, const float* __restrict__ Wk,
                        const float* __restrict__ Wv, unsigned short* __restrict__ Wtq,
                        unsigned short* __restrict__ Wtk, unsigned short* __restrict__ Wtv) {
  const int z = blockIdx.z;
  const float* W = (z == 0) ? Wq : (z == 1) ? Wk : Wv;
  unsigned short* Wt = (z == 0) ? Wtq : (z == 1) ? Wtk : Wtv;
  __shared__ float t[32][33];
  const int tid = threadIdx.x;
  const int row = tid >> 3, c4 = (tid & 7) * 4;
  float4 v = *(const float4*)(W + (size_t)(blockIdx.y * 32 + row) * ND + blockIdx.x * 32 + c4);
  t[row][c4] = v.x; t[row][c4 + 1] = v.y; t[row][c4 + 2] = v.z; t[row][c4 + 3] = v.w;
  __syncthreads();
  ushort4 o;
  o.x = f2b(t[c4][row]); o.y = f2b(t[c4 + 1][row]);
  o.z = f2b(t[c4 + 2][row]); o.w = f2b(t[c4 + 3][row]);
  *(ushort4*)(Wt + (size_t)(blockIdx.x * 32 + row) * ND + blockIdx.y * 32 + c4) = o;
}

// ---------------- QKV projection GEMM: [8192,1024]x[1024,1024] bf16, 128^2 tile ----------------
// z=0: Q (scaled by 0.125, layout [b,s,d]);  z=1: K ([b,s,d]);  z=2: V transposed -> Vt[b,h,hd,s]
__global__ __launch_bounds__(256) void qkv_gemm(
    const unsigned short* __restrict__ xb,
    const unsigned short* __restrict__ Wtq, const unsigned short* __restrict__ Wtk,
    const unsigned short* __restrict__ Wtv,
    const float* __restrict__ bq, const float* __restrict__ bk, const float* __restrict__ bv,
    unsigned short* __restrict__ Qb, unsigned short* __restrict__ Kb,
    unsigned short* __restrict__ Vt) {
  const int z = blockIdx.z;
  const unsigned short* Wt = (z == 0) ? Wtq : (z == 1) ? Wtk : Wtv;
  const float* bias = (z == 0) ? bq : (z == 1) ? bk : bv;
  const int tn = blockIdx.x, tm = blockIdx.y;
  __shared__ __align__(16) unsigned short Al[2][128 * 32];
  __shared__ __align__(16) unsigned short Bl[2][128 * 32];
  const int tid = threadIdx.x;
  const int lane = tid & 63, w = tid >> 6;
  const int c = lane & 15, g = lane >> 4;
  const int mo = (w >> 1) * 64, no = (w & 1) * 64;

  f32x4 acc[4][4];
#pragma unroll
  for (int i = 0; i < 4; i++)
#pragma unroll
    for (int j = 0; j < 4; j++) acc[i][j] = (f32x4){0.f, 0.f, 0.f, 0.f};

  // staging: linear LDS granule o*16B <-> (row=o>>2, gin=o&3); source inverse-swizzled
  const int r0 = tid >> 2, g0 = tid & 3;
  const int r1 = (256 + tid) >> 2, g1 = (256 + tid) & 3;
  const unsigned short* gA0 = xb + (size_t)(tm * 128 + r0) * ND + (g0 ^ sw2(r0)) * 8;
  const unsigned short* gA1 = xb + (size_t)(tm * 128 + r1) * ND + (g1 ^ sw2(r1)) * 8;
  const unsigned short* gB0 = Wt + (size_t)(tn * 128 + r0) * ND + (g0 ^ sw2(r0)) * 8;
  const unsigned short* gB1 = Wt + (size_t)(tn * 128 + r1) * ND + (g1 ^ sw2(r1)) * 8;
  const int lo0 = w * 512, lo1 = 2048 + w * 512;  // element offsets (wave-uniform)

  gload16(gA0, &Al[0][lo0]); gload16(gA1, &Al[0][lo1]);
  gload16(gB0, &Bl[0][lo0]); gload16(gB1, &Bl[0][lo1]);
  __syncthreads();

  for (int kk = 0; kk < 32; ++kk) {
    const int cur = kk & 1;
    if (kk < 31) {
      const int ko = (kk + 1) * 32;
      gload16(gA0 + ko, &Al[cur ^ 1][lo0]); gload16(gA1 + ko, &Al[cur ^ 1][lo1]);
      gload16(gB0 + ko, &Bl[cur ^ 1][lo0]); gload16(gB1 + ko, &Bl[cur ^ 1][lo1]);
    }
    short8 af[4], bf[4];
#pragma unroll
    for (int i = 0; i < 4; i++) {
      int row = mo + i * 16 + c;
      af[i] = *(const short8*)&Al[cur][row * 32 + (g ^ sw2(row)) * 8];
    }
#pragma unroll
    for (int j = 0; j < 4; j++) {
      int row = no + j * 16 + c;
      bf[j] = *(const short8*)&Bl[cur][row * 32 + (g ^ sw2(row)) * 8];
    }
#pragma unroll
    for (int i = 0; i < 4; i++)
#pragma unroll
      for (int j = 0; j < 4; j++)
        acc[i][j] = __builtin_amdgcn_mfma_f32_16x16x32_bf16(af[i], bf[j], acc[i][j], 0, 0, 0);
    __syncthreads();
  }

  // epilogue: C layout = D[row=4g+r][col=c]
  if (z < 2) {
    unsigned short* Out = (z == 0) ? Qb : Kb;
    const float sc = (z == 0) ? 0.125f : 1.0f;  // fold 1/sqrt(HD) into Q
#pragma unroll
    for (int j = 0; j < 4; j++) {
      int col = tn * 128 + no + j * 16 + c;
      float bv_ = bias[col];
#pragma unroll
      for (int i = 0; i < 4; i++) {
        int rowb = tm * 128 + mo + i * 16 + 4 * g;
#pragma unroll
        for (int r = 0; r < 4; r++) {
          float v = (acc[i][j][r] + bv_) * sc;
          float vn = __shfl_xor(v, 1, 64);
          if (!(lane & 1))
            *(unsigned int*)(Out + (size_t)(rowb + r) * ND + col) = pkbf(v, vn);
        }
      }
    }
  } else {
#pragma unroll
    for (int j = 0; j < 4; j++) {
      int col = tn * 128 + no + j * 16 + c;
      float bv_ = bias[col];
      int h = col >> 6, hd = col & 63;
#pragma unroll
      for (int i = 0; i < 4; i++) {
        int rowg = tm * 128 + mo + i * 16 + 4 * g;
        int bi = rowg >> 11, s = rowg & 2047;
        uint2 u;
        u.x = pkbf(acc[i][j][0] + bv_, acc[i][j][1] + bv_);
        u.y = pkbf(acc[i][j][2] + bv_, acc[i][j][3] + bv_);
        *(uint2*)(Vt + ((size_t)((bi * NH + h) * 64 + hd) * NS + s)) = u;
      }
    }
  }
}

// ---------------- flash attention + mean-over-S accumulation ----------------
// grid (qtile=32, h=16, b=4), 256 thr. Wave w: 16 queries. Swapped QK^T: E^T=mfma(K,Q).
__global__ __launch_bounds__(256) void attn_kernel(
    const unsigned short* __restrict__ Qb, const unsigned short* __restrict__ Kb,
    const unsigned short* __restrict__ Vt, float* __restrict__ mean_ctx) {
  const int qt = blockIdx.x, h = blockIdx.y, b = blockIdx.z;
  const int tid = threadIdx.x, lane = tid & 63, w = tid >> 6;
  const int c = lane & 15, g = lane >> 4;
  __shared__ __align__(16) unsigned short Klds[2][32 * 64];
  __shared__ __align__(16) unsigned short Vlds[2][64 * 32];
  __shared__ float redl[4][64];

  // hoisted Q fragments (B operand: col=q=c, k=hd=8g+j [+32])
  const int qg = qt * 64 + w * 16 + c;
  const unsigned short* qbase = Qb + (size_t)(b * NS + qg) * ND + h * 64 + g * 8;
  const short8 qf0 = *(const short8*)(qbase);
  const short8 qf1 = *(const short8*)(qbase + 32);

  // staging addrs (linear LDS dest, inverse-swizzled global source)
  const int krow = tid >> 3, kg = tid & 7;
  const unsigned short* gK = Kb + (size_t)(b * NS + krow) * ND + h * 64 + ((kg ^ (krow & 7)) * 8);
  const int vd = tid >> 2, vg = tid & 3;
  const unsigned short* gV = Vt + (size_t)((b * NH + h) * 64 + vd) * NS + ((vg ^ sw2(vd)) * 8);

  f32x4 accc[4];
#pragma unroll
  for (int nt = 0; nt < 4; nt++) accc[nt] = (f32x4){0.f, 0.f, 0.f, 0.f};
  float m_run = -1e30f, l_run = 0.f;

  gload16(gK, &Klds[0][w * 512]);
  gload16(gV, &Vlds[0][w * 512]);
  __syncthreads();

  for (int kc = 0; kc < 64; ++kc) {
    const int cur = kc & 1;
    if (kc < 63) {
      gload16(gK + (size_t)(kc + 1) * 32 * ND, &Klds[cur ^ 1][w * 512]);
      gload16(gV + (kc + 1) * 32, &Vlds[cur ^ 1][w * 512]);
    }
    // E^T = K * Q^T : A=K[key=16mt+c][hd], B=Q. D[row=key=4g+r(+16mt)][col=q=c]
    f32x4 accE[2];
#pragma unroll
    for (int mt = 0; mt < 2; ++mt) {
      int row = mt * 16 + c;
      short8 k0 = *(const short8*)&Klds[cur][row * 64 + ((g ^ (row & 7)) * 8)];
      short8 k1 = *(const short8*)&Klds[cur][row * 64 + (((g + 4) ^ (row & 7)) * 8)];
      f32x4 zz = (f32x4){0.f, 0.f, 0.f, 0.f};
      accE[mt] = __builtin_amdgcn_mfma_f32_16x16x32_bf16(k0, qf0, zz, 0, 0, 0);
      accE[mt] = __builtin_amdgcn_mfma_f32_16x16x32_bf16(k1, qf1, accE[mt], 0, 0, 0);
    }
    // online softmax for query c (4 redundant group-copies stay consistent)
    float cm = fmaxf(fmaxf(fmaxf(accE[0][0], accE[0][1]), fmaxf(accE[0][2], accE[0][3])),
                     fmaxf(fmaxf(accE[1][0], accE[1][1]), fmaxf(accE[1][2], accE[1][3])));
    cm = fmaxf(cm, __shfl_xor(cm, 16, 64));
    cm = fmaxf(cm, __shfl_xor(cm, 32, 64));
    float mnew = fmaxf(m_run, cm);
    float sf = __expf(m_run - mnew);
    float p[8];
#pragma unroll
    for (int r = 0; r < 4; r++) {
      p[r] = __expf(accE[0][r] - mnew);
      p[4 + r] = __expf(accE[1][r] - mnew);
    }
    float cs = ((p[0] + p[1]) + (p[2] + p[3])) + ((p[4] + p[5]) + (p[6] + p[7]));
    cs += __shfl_xor(cs, 16, 64);
    cs += __shfl_xor(cs, 32, 64);
    l_run = l_run * sf + cs;
    m_run = mnew;
    // rescale ctx acc (reg r holds query row 4g+r; fetch that query's sf from lane 4g+r)
    float sf0 = __shfl(sf, 4 * g + 0, 64), sf1 = __shfl(sf, 4 * g + 1, 64);
    float sf2 = __shfl(sf, 4 * g + 2, 64), sf3 = __shfl(sf, 4 * g + 3, 64);
#pragma unroll
    for (int nt = 0; nt < 4; nt++) {
      accc[nt][0] *= sf0; accc[nt][1] *= sf1; accc[nt][2] *= sf2; accc[nt][3] *= sf3;
    }
    // P redistribution: lane holds P[q=c][keys 4g+r, 16+4g+r]; A-frag needs P[q=c][key=8g+j].
    // Source lane for dest-g: srcA = c + 32*(g&1), srcB = srcA+16. Needed register bank
    // depends on DEST g (<2 -> pk0/pk1, >=2 -> pk2/pk3); shfl exports the SOURCE's reg,
    // so run both channels and select by dest g (fixes the r1 swapped-bank bug).
    unsigned int pk0 = pkbf(p[0], p[1]), pk1 = pkbf(p[2], p[3]);
    unsigned int pk2 = pkbf(p[4], p[5]), pk3 = pkbf(p[6], p[7]);
    int srcA = (g & 1) * 32 + c, srcB = srcA + 16;
    unsigned int a0 = (unsigned int)__shfl((int)pk0, srcA, 64);
    unsigned int h0 = (unsigned int)__shfl((int)pk2, srcA, 64);
    unsigned int a1 = (unsigned int)__shfl((int)pk1, srcA, 64);
    unsigned int h1 = (unsigned int)__shfl((int)pk3, srcA, 64);
    unsigned int a2 = (unsigned int)__shfl((int)pk0, srcB, 64);
    unsigned int h2 = (unsigned int)__shfl((int)pk2, srcB, 64);
    unsigned int a3 = (unsigned int)__shfl((int)pk1, srcB, 64);
    unsigned int h3 = (unsigned int)__shfl((int)pk3, srcB, 64);
    union { unsigned int u[4]; short8 v; } pf;
    pf.u[0] = (g < 2) ? a0 : h0;
    pf.u[1] = (g < 2) ? a1 : h1;
    pf.u[2] = (g < 2) ? a2 : h2;
    pf.u[3] = (g < 2) ? a3 : h3;
    // PV: A=P, B=V^T-lds (B[k=key=8g+j][col=d=16nt+c])
#pragma unroll
    for (int nt = 0; nt < 4; nt++) {
      int d = nt * 16 + c;
      short8 vf = *(const short8*)&Vlds[cur][d * 32 + ((g ^ sw2(d)) * 8)];
      accc[nt] = __builtin_amdgcn_mfma_f32_16x16x32_bf16(pf.v, vf, accc[nt], 0, 0, 0);
    }
    __syncthreads();
  }

  // finalize: /l per query row, column-sum over the wave's 16 queries, block-reduce, atomic
  float i0 = 1.f / __shfl(l_run, 4 * g + 0, 64);
  float i1 = 1.f / __shfl(l_run, 4 * g + 1, 64);
  float i2 = 1.f / __shfl(l_run, 4 * g + 2, 64);
  float i3 = 1.f / __shfl(l_run, 4 * g + 3, 64);
#pragma unroll
  for (int nt = 0; nt < 4; nt++) {
    float s = accc[nt][0] * i0 + accc[nt][1] * i1 + accc[nt][2] * i2 + accc[nt][3] * i3;
    s += __shfl_xor(s, 16, 64);
    s += __shfl_xor(s, 32, 64);
    if (g == 0) redl[w][nt * 16 + c] = s;
  }
  __syncthreads();
  if (tid < 64) {
    float tot = redl[0][tid] + redl[1][tid] + redl[2][tid] + redl[3][tid];
    atomicAdd(&mean_ctx[(size_t)b * ND + h * 64 + tid], tot * (1.0f / (float)NS));
  }
}

// ---------------- out = mean_ctx @ Wo + bo (fp32) ----------------
__global__ void out_proj(const float* __restrict__ mc, const float* __restrict__ Wo,
                         const float* __restrict__ bo, float* __restrict__ out) {
  const int b = blockIdx.y;
  const int d = blockIdx.x * 256 + threadIdx.x;
  const float* m = mc + (size_t)b * ND;
  float acc = bo[d];
#pragma unroll 8
  for (int k = 0; k < ND; ++k) acc = fmaf(m[k], Wo[(size_t)k * ND + d], acc);
  out[(size_t)b * ND + d] = acc;
}

extern "C" void kernel_launch(void* const* d_in, const int* in_sizes, int n_in,
                              void* d_out, int out_size, void* d_ws, size_t ws_size,
                              hipStream_t stream) {
  const float* x  = (const float*)d_in[0];
  const float* Wq = (const float*)d_in[1];
  const float* bq = (const float*)d_in[2];
  const float* Wk = (const float*)d_in[3];
  const float* bk = (const float*)d_in[4];
  const float* Wv = (const float*)d_in[5];
  const float* bv = (const float*)d_in[6];
  const float* Wo = (const float*)d_in[7];
  const float* bo = (const float*)d_in[8];
  float* out = (float*)d_out;

  char* ws = (char*)d_ws;
  size_t off = 0;
  unsigned short* xb  = (unsigned short*)(ws + off); off += (size_t)NB * NS * ND * 2;
  unsigned short* Wtq = (unsigned short*)(ws + off); off += (size_t)ND * ND * 2;
  unsigned short* Wtk = (unsigned short*)(ws + off); off += (size_t)ND * ND * 2;
  unsigned short* Wtv = (unsigned short*)(ws + off); off += (size_t)ND * ND * 2;
  unsigned short* Qb  = (unsigned short*)(ws + off); off += (size_t)NB * NS * ND * 2;
  unsigned short* Kb  = (unsigned short*)(ws + off); off += (size_t)NB * NS * ND * 2;
  unsigned short* Vt  = (unsigned short*)(ws + off); off += (size_t)NB * NS * ND * 2;
  float* mctx = (float*)(ws + off); off += (size_t)NB * ND * 4;

  hipMemsetAsync(mctx, 0, (size_t)NB * ND * 4, stream);
  conv_x<<<(NB * NS * ND / 4) / 256, 256, 0, stream>>>(x, xb);
  conv_wt<<<dim3(32, 32, 3), 256, 0, stream>>>(Wq, Wk, Wv, Wtq, Wtk, Wtv);
  qkv_gemm<<<dim3(ND / 128, NB * NS / 128, 3), 256, 0, stream>>>(
      xb, Wtq, Wtk, Wtv, bq, bk, bv, Qb, Kb, Vt);
  attn_kernel<<<dim3(NS / 64, NH, NB), 256, 0, stream>>>(Qb, Kb, Vt, mctx);
  out_proj<<<dim3(ND / 256, NB), 256, 0, stream>>>(mctx, Wo, bo, out);
}

// Round 6
// 403.116 us; speedup vs baseline: 1.0846x; 1.0846x over previous
//
#include <hip/hip_runtime.h>
#include <hip/hip_bf16.h>

// B=4, S=2048, D=1024, H=16, HD=64. fp32 in/out, bf16 MFMA compute inside.
#define NB 4
#define NS 2048
#define ND 1024
#define NH 16

typedef __attribute__((ext_vector_type(8))) short short8;
typedef __attribute__((ext_vector_type(4))) float f32x4;
typedef __attribute__((ext_vector_type(16))) float f32x16;
typedef __attribute__((ext_vector_type(2))) int v2i;

__device__ __forceinline__ unsigned short f2b(float f) {
  unsigned int u = __float_as_uint(f);
  u = (u + 0x7fffu + ((u >> 16) & 1u)) >> 16;   // RNE to bf16
  return (unsigned short)u;
}
__device__ __forceinline__ unsigned int pkbf(float a, float b) {
  return (unsigned int)f2b(a) | ((unsigned int)f2b(b) << 16);
}
__device__ __forceinline__ unsigned int cvtpk(float lo, float hi) {
  unsigned int r;
  asm("v_cvt_pk_bf16_f32 %0, %1, %2" : "=v"(r) : "v"(lo), "v"(hi));
  return r;
}
__device__ __forceinline__ v2i plswap(unsigned int a, unsigned int b) {
  return __builtin_amdgcn_permlane32_swap((int)a, (int)b, false, false);
}
__device__ __forceinline__ void gload16(const void* g, void* l) {
  __builtin_amdgcn_global_load_lds(
      (const __attribute__((address_space(1))) unsigned int*)g,
      (__attribute__((address_space(3))) unsigned int*)l, 16, 0, 0);
}
__device__ __forceinline__ int sw2(int row) { return (row ^ (row >> 2)) & 3; }

// ---------------- cast x -> bf16 ----------------
__global__ void conv_x(const float* __restrict__ x, unsigned short* __restrict__ xb) {
  int i = blockIdx.x * 256 + threadIdx.x;
  float4 v = ((const float4*)x)[i];
  ushort4 o;
  o.x = f2b(v.x); o.y = f2b(v.y); o.z = f2b(v.z); o.w = f2b(v.w);
  ((ushort4*)xb)[i] = o;
}

// ---------------- transpose + cast W[k][n] -> Wt_bf16[n][k] ----------------
__global__ void conv_wt(const float* __restrict__ Wq, const float* __restrict__ Wk,
                        const float* __restrict__ Wv, unsigned short* __restrict__ Wtq,
                        unsigned short* __restrict__ Wtk, unsigned short* __restrict__ Wtv) {
  const int z = blockIdx.z;
  const float* W = (z == 0) ? Wq : (z == 1) ? Wk : Wv;
  unsigned short* Wt = (z == 0) ? Wtq : (z == 1) ? Wtk : Wtv;
  __shared__ float t[32][33];
  const int tid = threadIdx.x;
  const int row = tid >> 3, c4 = (tid & 7) * 4;
  float4 v = *(const float4*)(W + (size_t)(blockIdx.y * 32 + row) * ND + blockIdx.x * 32 + c4);
  t[row][c4] = v.x; t[row][c4 + 1] = v.y; t[row][c4 + 2] = v.z; t[row][c4 + 3] = v.w;
  __syncthreads();
  ushort4 o;
  o.x = f2b(t[c4][row]); o.y = f2b(t[c4 + 1][row]);
  o.z = f2b(t[c4 + 2][row]); o.w = f2b(t[c4 + 3][row]);
  *(ushort4*)(Wt + (size_t)(blockIdx.x * 32 + row) * ND + blockIdx.y * 32 + c4) = o;
}

// ---------------- QKV projection GEMM: [8192,1024]x[1024,1024] bf16, 128^2 tile ----------------
__global__ __launch_bounds__(256) void qkv_gemm(
    const unsigned short* __restrict__ xb,
    const unsigned short* __restrict__ Wtq, const unsigned short* __restrict__ Wtk,
    const unsigned short* __restrict__ Wtv,
    const float* __restrict__ bq, const float* __restrict__ bk, const float* __restrict__ bv,
    unsigned short* __restrict__ Qb, unsigned short* __restrict__ Kb,
    unsigned short* __restrict__ Vt) {
  const int z = blockIdx.z;
  const unsigned short* Wt = (z == 0) ? Wtq : (z == 1) ? Wtk : Wtv;
  const float* bias = (z == 0) ? bq : (z == 1) ? bk : bv;
  const int tn = blockIdx.x, tm = blockIdx.y;
  __shared__ __align__(16) unsigned short Al[2][128 * 32];
  __shared__ __align__(16) unsigned short Bl[2][128 * 32];
  const int tid = threadIdx.x;
  const int lane = tid & 63, w = tid >> 6;
  const int c = lane & 15, g = lane >> 4;
  const int mo = (w >> 1) * 64, no = (w & 1) * 64;

  f32x4 acc[4][4];
#pragma unroll
  for (int i = 0; i < 4; i++)
#pragma unroll
    for (int j = 0; j < 4; j++) acc[i][j] = (f32x4){0.f, 0.f, 0.f, 0.f};

  const int r0 = tid >> 2, g0 = tid & 3;
  const int r1 = (256 + tid) >> 2, g1 = (256 + tid) & 3;
  const unsigned short* gA0 = xb + (size_t)(tm * 128 + r0) * ND + (g0 ^ sw2(r0)) * 8;
  const unsigned short* gA1 = xb + (size_t)(tm * 128 + r1) * ND + (g1 ^ sw2(r1)) * 8;
  const unsigned short* gB0 = Wt + (size_t)(tn * 128 + r0) * ND + (g0 ^ sw2(r0)) * 8;
  const unsigned short* gB1 = Wt + (size_t)(tn * 128 + r1) * ND + (g1 ^ sw2(r1)) * 8;
  const int lo0 = w * 512, lo1 = 2048 + w * 512;

  gload16(gA0, &Al[0][lo0]); gload16(gA1, &Al[0][lo1]);
  gload16(gB0, &Bl[0][lo0]); gload16(gB1, &Bl[0][lo1]);
  __syncthreads();

  for (int kk = 0; kk < 32; ++kk) {
    const int cur = kk & 1;
    if (kk < 31) {
      const int ko = (kk + 1) * 32;
      gload16(gA0 + ko, &Al[cur ^ 1][lo0]); gload16(gA1 + ko, &Al[cur ^ 1][lo1]);
      gload16(gB0 + ko, &Bl[cur ^ 1][lo0]); gload16(gB1 + ko, &Bl[cur ^ 1][lo1]);
    }
    short8 af[4], bf[4];
#pragma unroll
    for (int i = 0; i < 4; i++) {
      int row = mo + i * 16 + c;
      af[i] = *(const short8*)&Al[cur][row * 32 + (g ^ sw2(row)) * 8];
    }
#pragma unroll
    for (int j = 0; j < 4; j++) {
      int row = no + j * 16 + c;
      bf[j] = *(const short8*)&Bl[cur][row * 32 + (g ^ sw2(row)) * 8];
    }
#pragma unroll
    for (int i = 0; i < 4; i++)
#pragma unroll
      for (int j = 0; j < 4; j++)
        acc[i][j] = __builtin_amdgcn_mfma_f32_16x16x32_bf16(af[i], bf[j], acc[i][j], 0, 0, 0);
    __syncthreads();
  }

  if (z < 2) {
    unsigned short* Out = (z == 0) ? Qb : Kb;
    const float sc = (z == 0) ? 0.125f : 1.0f;  // fold 1/sqrt(HD) into Q
#pragma unroll
    for (int j = 0; j < 4; j++) {
      int col = tn * 128 + no + j * 16 + c;
      float bv_ = bias[col];
#pragma unroll
      for (int i = 0; i < 4; i++) {
        int rowb = tm * 128 + mo + i * 16 + 4 * g;
#pragma unroll
        for (int r = 0; r < 4; r++) {
          float v = (acc[i][j][r] + bv_) * sc;
          float vn = __shfl_xor(v, 1, 64);
          if (!(lane & 1))
            *(unsigned int*)(Out + (size_t)(rowb + r) * ND + col) = pkbf(v, vn);
        }
      }
    }
  } else {
#pragma unroll
    for (int j = 0; j < 4; j++) {
      int col = tn * 128 + no + j * 16 + c;
      float bv_ = bias[col];
      int h = col >> 6, hd = col & 63;
#pragma unroll
      for (int i = 0; i < 4; i++) {
        int rowg = tm * 128 + mo + i * 16 + 4 * g;
        int bi = rowg >> 11, s = rowg & 2047;
        uint2 u;
        u.x = pkbf(acc[i][j][0] + bv_, acc[i][j][1] + bv_);
        u.y = pkbf(acc[i][j][2] + bv_, acc[i][j][3] + bv_);
        *(uint2*)(Vt + ((size_t)((bi * NH + h) * 64 + hd) * NS + s)) = u;
      }
    }
  }
}

// ---------------- flash attention v2: 4 waves x 64q, KVBLK=64, 32x32x16 MFMA ----------------
// Swapped QK^T: E^T = mfma(K, Q) -> col = query = lane&31 (row lane-local softmax).
// P redistribution: cvt_pk_bf16 + permlane32_swap (T12). Defer-max rescale (T13, THR=8).
// Deterministic mean reduction: per-qt partial stores (no atomics).
__device__ __forceinline__ void softmax_pack(const f32x16& e, float& m, float& l,
                                             f32x16& c0, f32x16& c1, int hi,
                                             short8* pa) {
  float pm = e[0];
#pragma unroll
  for (int r = 1; r < 16; r++) pm = fmaxf(pm, e[r]);
  pm = fmaxf(pm, __shfl_xor(pm, 32, 64));
  if (__any(pm > m + 8.f)) {          // rare after warmup (defer-max)
    float mn = fmaxf(m, pm);
    float sf = __expf(m - mn);
#pragma unroll
    for (int r = 0; r < 16; r++) {
      int qlr = (r & 3) + 8 * (r >> 2) + 4 * hi;  // ctx row r = query qlr
      float sr = __shfl(sf, qlr, 64);
      c0[r] *= sr; c1[r] *= sr;
    }
    l *= sf; m = mn;
  }
  float p[16];
#pragma unroll
  for (int r = 0; r < 16; r++) p[r] = __expf(e[r] - m);
  float cs = 0.f;
#pragma unroll
  for (int r = 0; r < 16; r++) cs += p[r];
  cs += __shfl_xor(cs, 32, 64);
  l += cs;
  // quad m: keys 8m+4hi+{0..3} in regs 4m..4m+3
  unsigned int u0[4], u1[4];
#pragma unroll
  for (int mq = 0; mq < 4; mq++) {
    u0[mq] = cvtpk(p[4 * mq], p[4 * mq + 1]);
    u1[mq] = cvtpk(p[4 * mq + 2], p[4 * mq + 3]);
  }
#pragma unroll
  for (int si = 0; si < 2; si++) {
    v2i a = plswap(u0[2 * si], u0[2 * si + 1]);   // -> w0 (keys +0,+1), w2 (+4,+5)
    v2i bb = plswap(u1[2 * si], u1[2 * si + 1]);  // -> w1 (+2,+3),     w3 (+6,+7)
    union { unsigned int u[4]; short8 v; } pf;
    pf.u[0] = (unsigned int)a[0];
    pf.u[1] = (unsigned int)bb[0];
    pf.u[2] = (unsigned int)a[1];
    pf.u[3] = (unsigned int)bb[1];
    pa[si] = pf.v;
  }
}

__global__ __launch_bounds__(256) void attn_kernel(
    const unsigned short* __restrict__ Qb, const unsigned short* __restrict__ Kb,
    const unsigned short* __restrict__ Vt, float* __restrict__ mean_part) {
  const int qt = blockIdx.x, h = blockIdx.y, b = blockIdx.z;
  const int tid = threadIdx.x, lane = tid & 63, w = tid >> 6;
  const int ql_ = lane & 31, hi = lane >> 5;

  __shared__ __align__(16) unsigned short Kl[2][64 * 64];  // [key][hd], granule-swizzled
  __shared__ __align__(16) unsigned short Vl[2][64 * 64];  // [hd][key], granule-swizzled
  __shared__ float redl[4][64];

  // Q fragments qf[qg][s]: B-operand col=q=lane&31, k=16s+8hi+j
  short8 qf[2][4];
#pragma unroll
  for (int qg = 0; qg < 2; qg++) {
    const unsigned short* qb =
        Qb + ((size_t)b * NS + qt * 256 + w * 64 + qg * 32 + ql_) * ND + h * 64 + 8 * hi;
#pragma unroll
    for (int s = 0; s < 4; s++) qf[qg][s] = *(const short8*)(qb + 16 * s);
  }

  // staging: linear LDS dest (wave-uniform base), inverse-swizzled global source
  const int rid = tid >> 3, gcol = tid & 7;
  const int gsw = (gcol ^ (rid & 7)) * 8;
  const unsigned short* gK0 = Kb + ((size_t)b * NS + rid) * ND + h * 64 + gsw;
  const unsigned short* gK1 = gK0 + (size_t)32 * ND;
  const unsigned short* gV0 = Vt + ((size_t)(b * NH + h) * 64 + rid) * NS + gsw;
  const unsigned short* gV1 = gV0 + (size_t)32 * NS;

#define STAGE_KV(buf, kc)                                              \
  {                                                                    \
    const size_t ko = (size_t)(kc) * 64;                               \
    gload16(gK0 + ko * ND, &Kl[buf][w * 512]);                         \
    gload16(gK1 + ko * ND, &Kl[buf][2048 + w * 512]);                  \
    gload16(gV0 + ko, &Vl[buf][w * 512]);                              \
    gload16(gV1 + ko, &Vl[buf][2048 + w * 512]);                       \
  }

  const f32x16 Z16 = {0.f, 0.f, 0.f, 0.f, 0.f, 0.f, 0.f, 0.f,
                      0.f, 0.f, 0.f, 0.f, 0.f, 0.f, 0.f, 0.f};
  f32x16 ctx00 = Z16, ctx01 = Z16, ctx10 = Z16, ctx11 = Z16;  // [qg][dg]
  float m0 = -1e30f, m1 = -1e30f, l0 = 0.f, l1 = 0.f;

  STAGE_KV(0, 0);
  __syncthreads();

  for (int kc = 0; kc < 32; ++kc) {
    const int cur = kc & 1;
    if (kc < 31) STAGE_KV(cur ^ 1, kc + 1);
#pragma unroll
    for (int kg = 0; kg < 2; kg++) {
      // K A-frags: row=key=kg*32+ql_, k=16s+8hi+j
      short8 kf[4];
#pragma unroll
      for (int s = 0; s < 4; s++)
        kf[s] = *(const short8*)&Kl[cur][(kg * 32 + ql_) * 64 +
                                         (((2 * s + hi) ^ (ql_ & 7)) * 8)];
      __builtin_amdgcn_s_setprio(1);
      f32x16 e0 = __builtin_amdgcn_mfma_f32_32x32x16_bf16(kf[0], qf[0][0], Z16, 0, 0, 0);
      f32x16 e1 = __builtin_amdgcn_mfma_f32_32x32x16_bf16(kf[0], qf[1][0], Z16, 0, 0, 0);
#pragma unroll
      for (int s = 1; s < 4; s++) {
        e0 = __builtin_amdgcn_mfma_f32_32x32x16_bf16(kf[s], qf[0][s], e0, 0, 0, 0);
        e1 = __builtin_amdgcn_mfma_f32_32x32x16_bf16(kf[s], qf[1][s], e1, 0, 0, 0);
      }
      __builtin_amdgcn_s_setprio(0);

      short8 pa0[2], pa1[2];
      softmax_pack(e0, m0, l0, ctx00, ctx01, hi, pa0);
      softmax_pack(e1, m1, l1, ctx10, ctx11, hi, pa1);

      __builtin_amdgcn_s_setprio(1);
#pragma unroll
      for (int si = 0; si < 2; si++) {
#pragma unroll
        for (int dg = 0; dg < 2; dg++) {
          short8 vf = *(const short8*)&Vl[cur][(dg * 32 + ql_) * 64 +
                        (((4 * kg + 2 * si + hi) ^ (ql_ & 7)) * 8)];
          if (dg == 0) {
            ctx00 = __builtin_amdgcn_mfma_f32_32x32x16_bf16(pa0[si], vf, ctx00, 0, 0, 0);
            ctx10 = __builtin_amdgcn_mfma_f32_32x32x16_bf16(pa1[si], vf, ctx10, 0, 0, 0);
          } else {
            ctx01 = __builtin_amdgcn_mfma_f32_32x32x16_bf16(pa0[si], vf, ctx01, 0, 0, 0);
            ctx11 = __builtin_amdgcn_mfma_f32_32x32x16_bf16(pa1[si], vf, ctx11, 0, 0, 0);
          }
        }
      }
      __builtin_amdgcn_s_setprio(0);
    }
    __syncthreads();
  }

  // epilogue: sum_q ctx[q][d]/l[q]; ctx row r = query (r&3)+8*(r>>2)+4*hi (+32*qg)
  float linv0 = 1.f / l0, linv1 = 1.f / l1;
  float s0 = 0.f, s1 = 0.f;
#pragma unroll
  for (int r = 0; r < 16; r++) {
    int qlr = (r & 3) + 8 * (r >> 2) + 4 * hi;
    float lv0 = __shfl(linv0, qlr, 64);
    float lv1 = __shfl(linv1, qlr, 64);
    s0 += ctx00[r] * lv0 + ctx10[r] * lv1;
    s1 += ctx01[r] * lv0 + ctx11[r] * lv1;
  }
  s0 += __shfl_xor(s0, 32, 64);
  s1 += __shfl_xor(s1, 32, 64);
  if (lane < 32) { redl[w][lane] = s0; redl[w][32 + lane] = s1; }
  __syncthreads();
  if (tid < 64) {
    float tot = redl[0][tid] + redl[1][tid] + redl[2][tid] + redl[3][tid];
    mean_part[((size_t)qt * NB + b) * ND + h * 64 + tid] = tot * (1.0f / (float)NS);
  }
}

// ---------------- deterministic partial reduction: mctx[b][d] = sum_qt mp[qt][b][d] ----------------
__global__ void reduce_mctx(const float* __restrict__ mp, float* __restrict__ mctx) {
  int i = blockIdx.x * 256 + threadIdx.x;  // i = b*ND + d, 0..NB*ND-1
  float s = 0.f;
#pragma unroll
  for (int q = 0; q < NS / 256; ++q) s += mp[(size_t)q * NB * ND + i];
  mctx[i] = s;
}

// ---------------- out = mean_ctx @ Wo + bo (fp32) ----------------
__global__ void out_proj(const float* __restrict__ mc, const float* __restrict__ Wo,
                         const float* __restrict__ bo, float* __restrict__ out) {
  const int b = blockIdx.y;
  const int d = blockIdx.x * 256 + threadIdx.x;
  const float* m = mc + (size_t)b * ND;
  float acc = bo[d];
#pragma unroll 8
  for (int k = 0; k < ND; ++k) acc = fmaf(m[k], Wo[(size_t)k * ND + d], acc);
  out[(size_t)b * ND + d] = acc;
}

extern "C" void kernel_launch(void* const* d_in, const int* in_sizes, int n_in,
                              void* d_out, int out_size, void* d_ws, size_t ws_size,
                              hipStream_t stream) {
  const float* x  = (const float*)d_in[0];
  const float* Wq = (const float*)d_in[1];
  const float* bq = (const float*)d_in[2];
  const float* Wk = (const float*)d_in[3];
  const float* bk = (const float*)d_in[4];
  const float* Wv = (const float*)d_in[5];
  const float* bv = (const float*)d_in[6];
  const float* Wo = (const float*)d_in[7];
  const float* bo = (const float*)d_in[8];
  float* out = (float*)d_out;

  char* ws = (char*)d_ws;
  size_t off = 0;
  unsigned short* xb  = (unsigned short*)(ws + off); off += (size_t)NB * NS * ND * 2;
  unsigned short* Wtq = (unsigned short*)(ws + off); off += (size_t)ND * ND * 2;
  unsigned short* Wtk = (unsigned short*)(ws + off); off += (size_t)ND * ND * 2;
  unsigned short* Wtv = (unsigned short*)(ws + off); off += (size_t)ND * ND * 2;
  unsigned short* Qb  = (unsigned short*)(ws + off); off += (size_t)NB * NS * ND * 2;
  unsigned short* Kb  = (unsigned short*)(ws + off); off += (size_t)NB * NS * ND * 2;
  unsigned short* Vt  = (unsigned short*)(ws + off); off += (size_t)NB * NS * ND * 2;
  float* mpart = (float*)(ws + off); off += (size_t)(NS / 256) * NB * ND * 4;
  float* mctx  = (float*)(ws + off); off += (size_t)NB * ND * 4;

  conv_x<<<(NB * NS * ND / 4) / 256, 256, 0, stream>>>(x, xb);
  conv_wt<<<dim3(32, 32, 3), 256, 0, stream>>>(Wq, Wk, Wv, Wtq, Wtk, Wtv);
  qkv_gemm<<<dim3(ND / 128, NB * NS / 128, 3), 256, 0, stream>>>(
      xb, Wtq, Wtk, Wtv, bq, bk, bv, Qb, Kb, Vt);
  attn_kernel<<<dim3(NS / 256, NH, NB), 256, 0, stream>>>(Qb, Kb, Vt, mpart);
  reduce_mctx<<<(NB * ND) / 256, 256, 0, stream>>>(mpart, mctx);
  out_proj<<<dim3(ND / 256, NB), 256, 0, stream>>>(mctx, Wo, bo, out);
}

// Round 8
// 354.494 us; speedup vs baseline: 1.2333x; 1.1372x over previous
//
#include <hip/hip_runtime.h>
#include <hip/hip_bf16.h>

// B=4, S=2048, D=1024, H=16, HD=64. fp32 in/out, bf16 MFMA compute inside.
#define NB 4
#define NS 2048
#define ND 1024
#define NH 16

typedef __attribute__((ext_vector_type(8))) short short8;
typedef __attribute__((ext_vector_type(4))) float f32x4;
typedef __attribute__((ext_vector_type(16))) float f32x16;
typedef __attribute__((ext_vector_type(2))) int v2i;

__device__ __forceinline__ unsigned short f2b(float f) {
  unsigned int u = __float_as_uint(f);
  u = (u + 0x7fffu + ((u >> 16) & 1u)) >> 16;   // RNE to bf16
  return (unsigned short)u;
}
__device__ __forceinline__ unsigned int pkbf(float a, float b) {
  return (unsigned int)f2b(a) | ((unsigned int)f2b(b) << 16);
}
__device__ __forceinline__ unsigned int cvtpk(float lo, float hi) {
  unsigned int r;
  asm("v_cvt_pk_bf16_f32 %0, %1, %2" : "=v"(r) : "v"(lo), "v"(hi));
  return r;
}
__device__ __forceinline__ v2i plswap(unsigned int a, unsigned int b) {
  return __builtin_amdgcn_permlane32_swap((int)a, (int)b, false, false);
}
__device__ __forceinline__ void gload16(const void* g, void* l) {
  __builtin_amdgcn_global_load_lds(
      (const __attribute__((address_space(1))) unsigned int*)g,
      (__attribute__((address_space(3))) unsigned int*)l, 16, 0, 0);
}
__device__ __forceinline__ int sw2(int row) { return (row ^ (row >> 2)) & 3; }

// ---------------- cast x -> bf16 ----------------
__global__ void conv_x(const float* __restrict__ x, unsigned short* __restrict__ xb) {
  int i = blockIdx.x * 256 + threadIdx.x;
  float4 v = ((const float4*)x)[i];
  ushort4 o;
  o.x = f2b(v.x); o.y = f2b(v.y); o.z = f2b(v.z); o.w = f2b(v.w);
  ((ushort4*)xb)[i] = o;
}

// ---------------- transpose + cast W[k][n] -> Wt_bf16[n][k] ----------------
__global__ void conv_wt(const float* __restrict__ Wq, const float* __restrict__ Wk,
                        const float* __restrict__ Wv, unsigned short* __restrict__ Wtq,
                        unsigned short* __restrict__ Wtk, unsigned short* __restrict__ Wtv) {
  const int z = blockIdx.z;
  const float* W = (z == 0) ? Wq : (z == 1) ? Wk : Wv;
  unsigned short* Wt = (z == 0) ? Wtq : (z == 1) ? Wtk : Wtv;
  __shared__ float t[32][33];
  const int tid = threadIdx.x;
  const int row = tid >> 3, c4 = (tid & 7) * 4;
  float4 v = *(const float4*)(W + (size_t)(blockIdx.y * 32 + row) * ND + blockIdx.x * 32 + c4);
  t[row][c4] = v.x; t[row][c4 + 1] = v.y; t[row][c4 + 2] = v.z; t[row][c4 + 3] = v.w;
  __syncthreads();
  ushort4 o;
  o.x = f2b(t[c4][row]); o.y = f2b(t[c4 + 1][row]);
  o.z = f2b(t[c4 + 2][row]); o.w = f2b(t[c4 + 3][row]);
  *(ushort4*)(Wt + (size_t)(blockIdx.x * 32 + row) * ND + blockIdx.y * 32 + c4) = o;
}

// ---------------- QKV projection GEMM: [8192,1024]x[1024,1024] bf16, 128^2 tile ----------------
__global__ __launch_bounds__(256) void qkv_gemm(
    const unsigned short* __restrict__ xb,
    const unsigned short* __restrict__ Wtq, const unsigned short* __restrict__ Wtk,
    const unsigned short* __restrict__ Wtv,
    const float* __restrict__ bq, const float* __restrict__ bk, const float* __restrict__ bv,
    unsigned short* __restrict__ Qb, unsigned short* __restrict__ Kb,
    unsigned short* __restrict__ Vt) {
  const int z = blockIdx.z;
  const unsigned short* Wt = (z == 0) ? Wtq : (z == 1) ? Wtk : Wtv;
  const float* bias = (z == 0) ? bq : (z == 1) ? bk : bv;
  const int tn = blockIdx.x, tm = blockIdx.y;
  __shared__ __align__(16) unsigned short Al[2][128 * 32];
  __shared__ __align__(16) unsigned short Bl[2][128 * 32];
  const int tid = threadIdx.x;
  const int lane = tid & 63, w = tid >> 6;
  const int c = lane & 15, g = lane >> 4;
  const int mo = (w >> 1) * 64, no = (w & 1) * 64;

  f32x4 acc[4][4];
#pragma unroll
  for (int i = 0; i < 4; i++)
#pragma unroll
    for (int j = 0; j < 4; j++) acc[i][j] = (f32x4){0.f, 0.f, 0.f, 0.f};

  const int r0 = tid >> 2, g0 = tid & 3;
  const int r1 = (256 + tid) >> 2, g1 = (256 + tid) & 3;
  const unsigned short* gA0 = xb + (size_t)(tm * 128 + r0) * ND + (g0 ^ sw2(r0)) * 8;
  const unsigned short* gA1 = xb + (size_t)(tm * 128 + r1) * ND + (g1 ^ sw2(r1)) * 8;
  const unsigned short* gB0 = Wt + (size_t)(tn * 128 + r0) * ND + (g0 ^ sw2(r0)) * 8;
  const unsigned short* gB1 = Wt + (size_t)(tn * 128 + r1) * ND + (g1 ^ sw2(r1)) * 8;
  const int lo0 = w * 512, lo1 = 2048 + w * 512;

  gload16(gA0, &Al[0][lo0]); gload16(gA1, &Al[0][lo1]);
  gload16(gB0, &Bl[0][lo0]); gload16(gB1, &Bl[0][lo1]);
  __syncthreads();

  for (int kk = 0; kk < 32; ++kk) {
    const int cur = kk & 1;
    if (kk < 31) {
      const int ko = (kk + 1) * 32;
      gload16(gA0 + ko, &Al[cur ^ 1][lo0]); gload16(gA1 + ko, &Al[cur ^ 1][lo1]);
      gload16(gB0 + ko, &Bl[cur ^ 1][lo0]); gload16(gB1 + ko, &Bl[cur ^ 1][lo1]);
    }
    short8 af[4], bf[4];
#pragma unroll
    for (int i = 0; i < 4; i++) {
      int row = mo + i * 16 + c;
      af[i] = *(const short8*)&Al[cur][row * 32 + (g ^ sw2(row)) * 8];
    }
#pragma unroll
    for (int j = 0; j < 4; j++) {
      int row = no + j * 16 + c;
      bf[j] = *(const short8*)&Bl[cur][row * 32 + (g ^ sw2(row)) * 8];
    }
#pragma unroll
    for (int i = 0; i < 4; i++)
#pragma unroll
      for (int j = 0; j < 4; j++)
        acc[i][j] = __builtin_amdgcn_mfma_f32_16x16x32_bf16(af[i], bf[j], acc[i][j], 0, 0, 0);
    __syncthreads();
  }

  if (z < 2) {
    unsigned short* Out = (z == 0) ? Qb : Kb;
    const float sc = (z == 0) ? 0.125f : 1.0f;  // fold 1/sqrt(HD) into Q
#pragma unroll
    for (int j = 0; j < 4; j++) {
      int col = tn * 128 + no + j * 16 + c;
      float bv_ = bias[col];
#pragma unroll
      for (int i = 0; i < 4; i++) {
        int rowb = tm * 128 + mo + i * 16 + 4 * g;
#pragma unroll
        for (int r = 0; r < 4; r++) {
          float v = (acc[i][j][r] + bv_) * sc;
          float vn = __shfl_xor(v, 1, 64);
          if (!(lane & 1))
            *(unsigned int*)(Out + (size_t)(rowb + r) * ND + col) = pkbf(v, vn);
        }
      }
    }
  } else {
#pragma unroll
    for (int j = 0; j < 4; j++) {
      int col = tn * 128 + no + j * 16 + c;
      float bv_ = bias[col];
      int h = col >> 6, hd = col & 63;
#pragma unroll
      for (int i = 0; i < 4; i++) {
        int rowg = tm * 128 + mo + i * 16 + 4 * g;
        int bi = rowg >> 11, s = rowg & 2047;
        uint2 u;
        u.x = pkbf(acc[i][j][0] + bv_, acc[i][j][1] + bv_);
        u.y = pkbf(acc[i][j][2] + bv_, acc[i][j][3] + bv_);
        *(uint2*)(Vt + ((size_t)((bi * NH + h) * 64 + hd) * NS + s)) = u;
      }
    }
  }
}

// ---------------- flash attention v3: 1024 blocks, 4 waves x 32q, KVBLK=64 ----------------
// Swapped QK^T: E^T = mfma(K, Q) -> col = query = lane&31 (row lane-local softmax).
// P redistribution: cvt_pk_bf16 + permlane32_swap (T12). Defer-max rescale (T13, THR=8).
// 128 queries/block -> 4 blocks/CU (16 waves/CU) for latency hiding; VGPR capped 128.
__device__ __forceinline__ void softmax_pack(const f32x16& e, float& m, float& l,
                                             f32x16& c0, f32x16& c1, int hi,
                                             short8* pa) {
  float pm = e[0];
#pragma unroll
  for (int r = 1; r < 16; r++) pm = fmaxf(pm, e[r]);
  pm = fmaxf(pm, __shfl_xor(pm, 32, 64));
  if (__any(pm > m + 8.f)) {          // rare after warmup (defer-max)
    float mn = fmaxf(m, pm);
    float sf = __expf(m - mn);
#pragma unroll
    for (int r = 0; r < 16; r++) {
      int qlr = (r & 3) + 8 * (r >> 2) + 4 * hi;  // ctx row r = query qlr
      float sr = __shfl(sf, qlr, 64);
      c0[r] *= sr; c1[r] *= sr;
    }
    l *= sf; m = mn;
  }
  float p[16];
#pragma unroll
  for (int r = 0; r < 16; r++) p[r] = __expf(e[r] - m);
  float cs = 0.f;
#pragma unroll
  for (int r = 0; r < 16; r++) cs += p[r];
  cs += __shfl_xor(cs, 32, 64);
  l += cs;
  // quad m: keys 8m+4hi+{0..3} in regs 4m..4m+3
  unsigned int u0[4], u1[4];
#pragma unroll
  for (int mq = 0; mq < 4; mq++) {
    u0[mq] = cvtpk(p[4 * mq], p[4 * mq + 1]);
    u1[mq] = cvtpk(p[4 * mq + 2], p[4 * mq + 3]);
  }
#pragma unroll
  for (int si = 0; si < 2; si++) {
    v2i a = plswap(u0[2 * si], u0[2 * si + 1]);   // -> w0 (keys +0,+1), w2 (+4,+5)
    v2i bb = plswap(u1[2 * si], u1[2 * si + 1]);  // -> w1 (+2,+3),     w3 (+6,+7)
    union { unsigned int u[4]; short8 v; } pf;
    pf.u[0] = (unsigned int)a[0];
    pf.u[1] = (unsigned int)bb[0];
    pf.u[2] = (unsigned int)a[1];
    pf.u[3] = (unsigned int)bb[1];
    pa[si] = pf.v;
  }
}

__global__ __launch_bounds__(256, 4) void attn_kernel(
    const unsigned short* __restrict__ Qb, const unsigned short* __restrict__ Kb,
    const unsigned short* __restrict__ Vt, float* __restrict__ mean_part) {
  const int qt = blockIdx.x, h = blockIdx.y, b = blockIdx.z;
  const int tid = threadIdx.x, lane = tid & 63, w = tid >> 6;
  const int ql_ = lane & 31, hi = lane >> 5;

  __shared__ __align__(16) unsigned short Kl[2][64 * 64];  // [key][hd], granule-swizzled
  __shared__ __align__(16) unsigned short Vl[2][64 * 64];  // [hd][key], granule-swizzled
  __shared__ float redl[4][64];

  // Q fragments: wave w owns queries qt*128 + w*32 + ql_; B-op col=q, k=16s+8hi+j
  const unsigned short* qb =
      Qb + ((size_t)b * NS + qt * 128 + w * 32 + ql_) * ND + h * 64 + 8 * hi;
  short8 qf[4];
#pragma unroll
  for (int s = 0; s < 4; s++) qf[s] = *(const short8*)(qb + 16 * s);

  // staging: linear LDS dest (wave-uniform base), inverse-swizzled global source
  const int rid = tid >> 3, gcol = tid & 7;
  const int gsw = (gcol ^ (rid & 7)) * 8;
  const unsigned short* gK0 = Kb + ((size_t)b * NS + rid) * ND + h * 64 + gsw;
  const unsigned short* gK1 = gK0 + (size_t)32 * ND;
  const unsigned short* gV0 = Vt + ((size_t)(b * NH + h) * 64 + rid) * NS + gsw;
  const unsigned short* gV1 = gV0 + (size_t)32 * NS;

#define STAGE_KV(buf, kc)                                              \
  {                                                                    \
    const size_t ko = (size_t)(kc) * 64;                               \
    gload16(gK0 + ko * ND, &Kl[buf][w * 512]);                         \
    gload16(gK1 + ko * ND, &Kl[buf][2048 + w * 512]);                  \
    gload16(gV0 + ko, &Vl[buf][w * 512]);                              \
    gload16(gV1 + ko, &Vl[buf][2048 + w * 512]);                       \
  }

  const f32x16 Z16 = {0.f, 0.f, 0.f, 0.f, 0.f, 0.f, 0.f, 0.f,
                      0.f, 0.f, 0.f, 0.f, 0.f, 0.f, 0.f, 0.f};
  f32x16 ctx0 = Z16, ctx1 = Z16;  // d = ql_ (dg=0), d = 32+ql_ (dg=1)
  float m0 = -1e30f, l0 = 0.f;

  STAGE_KV(0, 0);
  __syncthreads();

  for (int kc = 0; kc < 32; ++kc) {
    const int cur = kc & 1;
    if (kc < 31) STAGE_KV(cur ^ 1, kc + 1);
#pragma unroll
    for (int kg = 0; kg < 2; kg++) {
      // K A-frags: row=key=kg*32+ql_, k=16s+8hi+j
      short8 kf[4];
#pragma unroll
      for (int s = 0; s < 4; s++)
        kf[s] = *(const short8*)&Kl[cur][(kg * 32 + ql_) * 64 +
                                         (((2 * s + hi) ^ (ql_ & 7)) * 8)];
      __builtin_amdgcn_s_setprio(1);
      f32x16 e = __builtin_amdgcn_mfma_f32_32x32x16_bf16(kf[0], qf[0], Z16, 0, 0, 0);
#pragma unroll
      for (int s = 1; s < 4; s++)
        e = __builtin_amdgcn_mfma_f32_32x32x16_bf16(kf[s], qf[s], e, 0, 0, 0);
      __builtin_amdgcn_s_setprio(0);

      short8 pa[2];
      softmax_pack(e, m0, l0, ctx0, ctx1, hi, pa);

      __builtin_amdgcn_s_setprio(1);
#pragma unroll
      for (int si = 0; si < 2; si++) {
#pragma unroll
        for (int dg = 0; dg < 2; dg++) {
          short8 vf = *(const short8*)&Vl[cur][(dg * 32 + ql_) * 64 +
                        (((4 * kg + 2 * si + hi) ^ (ql_ & 7)) * 8)];
          if (dg == 0)
            ctx0 = __builtin_amdgcn_mfma_f32_32x32x16_bf16(pa[si], vf, ctx0, 0, 0, 0);
          else
            ctx1 = __builtin_amdgcn_mfma_f32_32x32x16_bf16(pa[si], vf, ctx1, 0, 0, 0);
        }
      }
      __builtin_amdgcn_s_setprio(0);
    }
    __syncthreads();
  }

  // epilogue: sum_q ctx[q][d]/l[q]; ctx row r = query (r&3)+8*(r>>2)+4*hi
  float linv = 1.f / l0;
  float s0 = 0.f, s1 = 0.f;
#pragma unroll
  for (int r = 0; r < 16; r++) {
    int qlr = (r & 3) + 8 * (r >> 2) + 4 * hi;
    float lv = __shfl(linv, qlr, 64);
    s0 += ctx0[r] * lv;
    s1 += ctx1[r] * lv;
  }
  s0 += __shfl_xor(s0, 32, 64);
  s1 += __shfl_xor(s1, 32, 64);
  if (lane < 32) { redl[w][lane] = s0; redl[w][32 + lane] = s1; }
  __syncthreads();
  if (tid < 64) {
    float tot = redl[0][tid] + redl[1][tid] + redl[2][tid] + redl[3][tid];
    mean_part[((size_t)qt * NB + b) * ND + h * 64 + tid] = tot * (1.0f / (float)NS);
  }
}

// ---------------- deterministic partial reduction: mctx[b][d] = sum_qt mp[qt][b][d] ----------------
__global__ void reduce_mctx(const float* __restrict__ mp, float* __restrict__ mctx) {
  int i = blockIdx.x * 256 + threadIdx.x;  // i = b*ND + d, 0..NB*ND-1
  float s = 0.f;
#pragma unroll
  for (int q = 0; q < NS / 128; ++q) s += mp[(size_t)q * NB * ND + i];
  mctx[i] = s;
}

// ---------------- out = mean_ctx @ Wo + bo (fp32) ----------------
__global__ void out_proj(const float* __restrict__ mc, const float* __restrict__ Wo,
                         const float* __restrict__ bo, float* __restrict__ out) {
  const int b = blockIdx.y;
  const int d = blockIdx.x * 256 + threadIdx.x;
  const float* m = mc + (size_t)b * ND;
  float acc = bo[d];
#pragma unroll 8
  for (int k = 0; k < ND; ++k) acc = fmaf(m[k], Wo[(size_t)k * ND + d], acc);
  out[(size_t)b * ND + d] = acc;
}

extern "C" void kernel_launch(void* const* d_in, const int* in_sizes, int n_in,
                              void* d_out, int out_size, void* d_ws, size_t ws_size,
                              hipStream_t stream) {
  const float* x  = (const float*)d_in[0];
  const float* Wq = (const float*)d_in[1];
  const float* bq = (const float*)d_in[2];
  const float* Wk = (const float*)d_in[3];
  const float* bk = (const float*)d_in[4];
  const float* Wv = (const float*)d_in[5];
  const float* bv = (const float*)d_in[6];
  const float* Wo = (const float*)d_in[7];
  const float* bo = (const float*)d_in[8];
  float* out = (float*)d_out;

  char* ws = (char*)d_ws;
  size_t off = 0;
  unsigned short* xb  = (unsigned short*)(ws + off); off += (size_t)NB * NS * ND * 2;
  unsigned short* Wtq = (unsigned short*)(ws + off); off += (size_t)ND * ND * 2;
  unsigned short* Wtk = (unsigned short*)(ws + off); off += (size_t)ND * ND * 2;
  unsigned short* Wtv = (unsigned short*)(ws + off); off += (size_t)ND * ND * 2;
  unsigned short* Qb  = (unsigned short*)(ws + off); off += (size_t)NB * NS * ND * 2;
  unsigned short* Kb  = (unsigned short*)(ws + off); off += (size_t)NB * NS * ND * 2;
  unsigned short* Vt  = (unsigned short*)(ws + off); off += (size_t)NB * NS * ND * 2;
  float* mpart = (float*)(ws + off); off += (size_t)(NS / 128) * NB * ND * 4;
  float* mctx  = (float*)(ws + off); off += (size_t)NB * ND * 4;

  conv_x<<<(NB * NS * ND / 4) / 256, 256, 0, stream>>>(x, xb);
  conv_wt<<<dim3(32, 32, 3), 256, 0, stream>>>(Wq, Wk, Wv, Wtq, Wtk, Wtv);
  qkv_gemm<<<dim3(ND / 128, NB * NS / 128, 3), 256, 0, stream>>>(
      xb, Wtq, Wtk, Wtv, bq, bk, bv, Qb, Kb, Vt);
  attn_kernel<<<dim3(NS / 128, NH, NB), 256, 0, stream>>>(Qb, Kb, Vt, mpart);
  reduce_mctx<<<(NB * ND) / 256, 256, 0, stream>>>(mpart, mctx);
  out_proj<<<dim3(ND / 256, NB), 256, 0, stream>>>(mctx, Wo, bo, out);
}